// Round 2
// baseline (949.672 us; speedup 1.0000x reference)
//
#include <hip/hip_runtime.h>
#include <stdint.h>

#define NHEADS 16
#define HDIM 32
#define NTOK 64
#define NWIN_B 2048
#define MROWS (NWIN_B * NTOK)   // 131072
#define CDIM 512
#define QKVDIM 1536
#define ATT_SCALE 0.17677669529663687f

typedef __attribute__((ext_vector_type(8))) short short8;
typedef __attribute__((ext_vector_type(4))) float f32x4;

__device__ __forceinline__ unsigned short f2bf(float f) {
  unsigned int u = __float_as_uint(f);
  u += 0x7FFFu + ((u >> 16) & 1u);   // RNE
  return (unsigned short)(u >> 16);
}

__device__ __forceinline__ void gload_lds16(const unsigned short* g, unsigned short* l) {
  __builtin_amdgcn_global_load_lds(
      (const __attribute__((address_space(1))) unsigned int*)g,
      (__attribute__((address_space(3))) unsigned int*)l, 16, 0, 0);
}

// ---------- fp32 -> bf16 convert ----------
__global__ void cvt_bf16_kernel(const float* __restrict__ src,
                                unsigned short* __restrict__ dst, int n4) {
  int i = blockIdx.x * blockDim.x + threadIdx.x;
  if (i >= n4) return;
  const float4 v = ((const float4*)src)[i];
  ushort4 o;
  o.x = f2bf(v.x); o.y = f2bf(v.y); o.z = f2bf(v.z); o.w = f2bf(v.w);
  ((ushort4*)dst)[i] = o;
}

// ---------- Swin relative-position bias expansion: bias[h][row][col] ----------
__global__ void expand_bias_kernel(const float* __restrict__ table,
                                   float* __restrict__ biasx) {
  const int t = blockIdx.x * blockDim.x + threadIdx.x;   // [0, 16*64*64)
  const int col = t & 63, row = (t >> 6) & 63, h = t >> 12;
  const int idx = ((row >> 3) - (col >> 3) + 7) * 15 + ((row & 7) - (col & 7) + 7);
  biasx[t] = table[idx * NHEADS + h];
}

// ================= shared 8-phase K-loop pieces (256x256, BK=64) =============
#define MMAQ(qm, qn)                                                          \
  do {                                                                        \
    _Pragma("unroll") for (int kk = 0; kk < 2; ++kk)                          \
    _Pragma("unroll") for (int mt = 0; mt < 4; ++mt)                          \
    _Pragma("unroll") for (int nt = 0; nt < 2; ++nt)                          \
      acc[(qm) * 4 + mt][(qn) * 2 + nt] =                                     \
          __builtin_amdgcn_mfma_f32_16x16x32_bf16(                            \
              aF[mt][kk], bF[(qn) * 2 + nt][kk],                              \
              acc[(qm) * 4 + mt][(qn) * 2 + nt], 0, 0, 0);                    \
  } while (0)

#define LDB_Q(buf, qn)                                                        \
  do {                                                                        \
    _Pragma("unroll") for (int nt = 0; nt < 2; ++nt) {                        \
      const int rb_ = wn * 64 + ((qn) * 2 + nt) * 16 + l16;                   \
      _Pragma("unroll") for (int kk = 0; kk < 2; ++kk) {                      \
        const int pb_ = ((kk * 4 + quad) ^ (l16 & 7)) * 8;                    \
        bF[(qn) * 2 + nt][kk] =                                               \
            *(const short8*)&lds[(buf) * BUFSZ + ATILE + rb_ * 64 + pb_];     \
      }                                                                       \
    }                                                                         \
  } while (0)

#define GEMM_KLOOP_BODY                                                       \
  stageA(0, 0, 0); stageA(0, 1, 0); stageB(0, 0, 0); stageB(0, 1, 0);         \
  if (NT > 1) { stageB(1, 0, 1); stageB(1, 1, 1); }                           \
  asm volatile("s_waitcnt vmcnt(4)" ::: "memory");                            \
  __builtin_amdgcn_s_barrier();                                               \
  for (int u = 0; u < NT; ++u) {                                              \
    const int cur = u & 1, nxt = cur ^ 1;                                     \
    ldA(cur, 0);                                                              \
    LDB_Q(cur, 0);                                                            \
    if (u + 1 < NT) stageA(nxt, 0, u + 1);                                    \
    asm volatile("s_waitcnt lgkmcnt(8)" ::: "memory");                        \
    __builtin_amdgcn_s_barrier();                                             \
    asm volatile("s_waitcnt lgkmcnt(0)" ::: "memory");                        \
    __builtin_amdgcn_sched_barrier(0);                                        \
    __builtin_amdgcn_s_setprio(1);                                            \
    MMAQ(0, 0);                                                               \
    __builtin_amdgcn_s_setprio(0);                                            \
    __builtin_amdgcn_s_barrier();                                             \
    LDB_Q(cur, 1);                                                            \
    if (u + 1 < NT) stageA(nxt, 1, u + 1);                                    \
    __builtin_amdgcn_s_barrier();                                             \
    asm volatile("s_waitcnt lgkmcnt(0)" ::: "memory");                        \
    __builtin_amdgcn_sched_barrier(0);                                        \
    __builtin_amdgcn_s_setprio(1);                                            \
    MMAQ(0, 1);                                                               \
    __builtin_amdgcn_s_setprio(0);                                            \
    __builtin_amdgcn_s_barrier();                                             \
    ldA(cur, 1);                                                              \
    if (u + 2 < NT) stageB(cur, 0, u + 2);                                    \
    __builtin_amdgcn_s_barrier();                                             \
    asm volatile("s_waitcnt lgkmcnt(0)" ::: "memory");                        \
    __builtin_amdgcn_sched_barrier(0);                                        \
    __builtin_amdgcn_s_setprio(1);                                            \
    MMAQ(1, 1);                                                               \
    __builtin_amdgcn_s_setprio(0);                                            \
    __builtin_amdgcn_s_barrier();                                             \
    if (u + 2 < NT) stageB(cur, 1, u + 2);                                    \
    __builtin_amdgcn_s_barrier();                                             \
    __builtin_amdgcn_s_setprio(1);                                            \
    MMAQ(1, 0);                                                               \
    __builtin_amdgcn_s_setprio(0);                                            \
    if (u + 1 < NT) {                                                         \
      if (u + 2 < NT) asm volatile("s_waitcnt vmcnt(4)" ::: "memory");        \
      else            asm volatile("s_waitcnt vmcnt(0)" ::: "memory");        \
    }                                                                         \
    __builtin_amdgcn_s_barrier();                                             \
  }

// ---------- QKV GEMM: qk[M][1024] = Q|K, V stored TRANSPOSED in vt ----------
// vt layout: [win*4 + headgroup][d=128][k=64] bf16 (d = col within head-group)
__global__ __launch_bounds__(512, 2) void gemm_qkv_kernel(
    const unsigned short* __restrict__ A,     // xb [M][512]
    const unsigned short* __restrict__ Bt,    // wqkvb [1536][512]
    const float* __restrict__ bias,
    unsigned short* __restrict__ qkOut,       // [M][1024]
    unsigned short* __restrict__ vtOut,       // [M/64*4][128][64]
    int M, int K, int nxb) {
  constexpr int BK = 64;
  constexpr int ATILE = 256 * BK;
  constexpr int BUFSZ = 2 * ATILE;
  __shared__ __align__(16) unsigned short lds[2 * BUFSZ];  // 128 KiB

  const int tid = threadIdx.x;
  const int w = tid >> 6, lane = tid & 63;
  const int quad = lane >> 4, l16 = lane & 15;
  const int wm = w >> 2, wn = w & 3;
  const int srow8 = lane >> 3, gch = (lane & 7) ^ srow8;

  const int nyb_per_xcd = (gridDim.x / nxb) >> 3;
  const int xcd = blockIdx.x & 7;
  const int idx = blockIdx.x >> 3;
  const long rowBase = (long)(xcd * nyb_per_xcd + idx / nxb) * 256;
  const long colBase = (long)(idx % nxb) * 256;
  const int NT = K / BK;

  const unsigned short* aSrc = A + (rowBase + w * 8 + srow8) * (long)K + gch * 8;
  const unsigned short* bSrc = Bt + (colBase + w * 8 + srow8) * (long)K + gch * 8;

  auto stageA = [&](int buf, int half, int kt) {
    unsigned short* dst = &lds[buf * BUFSZ + (half * 128 + w * 8) * BK];
    const unsigned short* src = aSrc + (long)half * 128 * K + kt * BK;
    gload_lds16(src, dst);
    gload_lds16(src + 64 * (long)K, dst + 64 * BK);
  };
  auto stageB = [&](int buf, int half, int kt) {
    unsigned short* dst = &lds[buf * BUFSZ + ATILE + (half * 128 + w * 8) * BK];
    const unsigned short* src = bSrc + (long)half * 128 * K + kt * BK;
    gload_lds16(src, dst);
    gload_lds16(src + 64 * (long)K, dst + 64 * BK);
  };

  f32x4 acc[8][4] = {};
  short8 aF[4][2], bF[4][2];

  auto ldA = [&](int buf, int qm) {
#pragma unroll
    for (int mt = 0; mt < 4; ++mt) {
      const int r = wm * 128 + qm * 64 + mt * 16 + l16;
#pragma unroll
      for (int kk = 0; kk < 2; ++kk) {
        const int p = ((kk * 4 + quad) ^ (l16 & 7)) * 8;
        aF[mt][kk] = *(const short8*)&lds[buf * BUFSZ + r * 64 + p];
      }
    }
  };

  GEMM_KLOOP_BODY

  // ---- epilogue: repack to Cs (bf16 + bias), then split Q/K vs V^T ----
  unsigned short* Cs = &lds[0];
#pragma unroll
  for (int ni = 0; ni < 4; ++ni) {
    const int col = wn * 64 + ni * 16 + l16;
    const float bv = bias[colBase + col];
#pragma unroll
    for (int mi = 0; mi < 8; ++mi) {
      const int row0 = wm * 128 + mi * 16 + quad * 4;
#pragma unroll
      for (int r = 0; r < 4; ++r)
        Cs[(row0 + r) * 256 + col] = f2bf(acc[mi][ni][r] + bv);
    }
  }
  __syncthreads();
  if (colBase < 1024) {
    // Q/K: row-major coalesced 16B stores into packed qk[M][1024]
#pragma unroll
    for (int t = 0; t < 16; ++t) {
      const int ci = t * 512 + tid;          // 8192 chunks of 16B
      const int row = ci >> 5, ch2 = ci & 31;
      *(short8*)(qkOut + (rowBase + row) * 1024 + colBase + ch2 * 8) =
          *(const short8*)&Cs[ci * 8];
    }
  } else {
    // V: transposed store. lanes sweep d (contiguous LDS reads, conflict-free)
    const int qpair = (int)((colBase - 1024) >> 7);   // 0 or 2
#pragma unroll
    for (int t = 0; t < 16; ++t) {
      const int ci = t * 512 + tid;
      const int d = ci & 127;
      const int k0 = (ci >> 7) & 7;
      const int slabi = ci >> 10;             // winloc*2 + qsel
      const int winloc = slabi >> 1, qsel = slabi & 1;
      short8 v;
#pragma unroll
      for (int j = 0; j < 8; ++j)
        v[j] = (short)Cs[(winloc * 64 + k0 * 8 + j) * 256 + qsel * 128 + d];
      const long slab = ((rowBase >> 6) + winloc) * 4 + qpair + qsel;
      *(short8*)(vtOut + slab * 8192 + (long)d * 64 + k0 * 8) = v;
    }
  }
}

// ---------- proj GEMM (unchanged 8-phase, f32 out) ----------
__global__ __launch_bounds__(512, 2) void gemm256_kernel(
    const unsigned short* __restrict__ A,
    const unsigned short* __restrict__ Bt,
    const float* __restrict__ bias,
    float* __restrict__ C, int M, int N, int K, int nxb) {
  constexpr int BK = 64;
  constexpr int ATILE = 256 * BK;
  constexpr int BUFSZ = 2 * ATILE;
  __shared__ __align__(16) unsigned short lds[2 * BUFSZ];  // 128 KiB

  const int tid = threadIdx.x;
  const int w = tid >> 6, lane = tid & 63;
  const int quad = lane >> 4, l16 = lane & 15;
  const int wm = w >> 2, wn = w & 3;
  const int srow8 = lane >> 3, gch = (lane & 7) ^ srow8;

  const int nyb_per_xcd = (gridDim.x / nxb) >> 3;
  const int xcd = blockIdx.x & 7;
  const int idx = blockIdx.x >> 3;
  const long rowBase = (long)(xcd * nyb_per_xcd + idx / nxb) * 256;
  const long colBase = (long)(idx % nxb) * 256;
  const int NT = K / BK;

  const unsigned short* aSrc = A + (rowBase + w * 8 + srow8) * (long)K + gch * 8;
  const unsigned short* bSrc = Bt + (colBase + w * 8 + srow8) * (long)K + gch * 8;

  auto stageA = [&](int buf, int half, int kt) {
    unsigned short* dst = &lds[buf * BUFSZ + (half * 128 + w * 8) * BK];
    const unsigned short* src = aSrc + (long)half * 128 * K + kt * BK;
    gload_lds16(src, dst);
    gload_lds16(src + 64 * (long)K, dst + 64 * BK);
  };
  auto stageB = [&](int buf, int half, int kt) {
    unsigned short* dst = &lds[buf * BUFSZ + ATILE + (half * 128 + w * 8) * BK];
    const unsigned short* src = bSrc + (long)half * 128 * K + kt * BK;
    gload_lds16(src, dst);
    gload_lds16(src + 64 * (long)K, dst + 64 * BK);
  };

  f32x4 acc[8][4] = {};
  short8 aF[4][2], bF[4][2];

  auto ldA = [&](int buf, int qm) {
#pragma unroll
    for (int mt = 0; mt < 4; ++mt) {
      const int r = wm * 128 + qm * 64 + mt * 16 + l16;
#pragma unroll
      for (int kk = 0; kk < 2; ++kk) {
        const int p = ((kk * 4 + quad) ^ (l16 & 7)) * 8;
        aF[mt][kk] = *(const short8*)&lds[buf * BUFSZ + r * 64 + p];
      }
    }
  };

  GEMM_KLOOP_BODY

#pragma unroll
  for (int ni = 0; ni < 4; ++ni) {
    const long col = colBase + wn * 64 + ni * 16 + l16;
    const float bv = bias[col];
#pragma unroll
    for (int mi = 0; mi < 8; ++mi) {
      const long row0 = rowBase + wm * 128 + mi * 16 + quad * 4;
#pragma unroll
      for (int r = 0; r < 4; ++r)
        C[(row0 + r) * N + col] = acc[mi][ni][r] + bv;
    }
  }
}

// ---------- attention: one block = one window x 4 heads ----------
// Q,K from packed qk[M][1024]; V^T from vt -> clean b128 PV fragments.
// O^T = mfma(A = V^T, B = P): both operands read as contiguous 16B rows.
__global__ __launch_bounds__(256) void attn_kernel(
    const unsigned short* __restrict__ qk,    // [MROWS][1024] bf16
    const unsigned short* __restrict__ vtg,   // [NWIN_B*4][128][64] bf16
    const float* __restrict__ biasx,          // [16][64][64]
    unsigned short* __restrict__ aout) {      // [MROWS][512] bf16
  // [0,16384): Q(0..8191) K(8192..16383); later P overlays [0,18432)
  // [18432,26624): Vt [128][64]; later Ot [64][128] overlays same region
  __shared__ __align__(16) unsigned short sm[26624];   // 52 KB
  unsigned short* P  = sm;
  unsigned short* Vt = sm + 18432;
  unsigned short* Ot = sm + 18432;

  const int tid = threadIdx.x;
  const int w = tid >> 6, lane = tid & 63;
  const int quad = lane >> 4, l16 = lane & 15;
  const int b = blockIdx.x >> 2;
  const int q = blockIdx.x & 3;       // head group: heads q*4 .. q*4+3
  const int h = q * 4 + w;

  // ---- stage Q,K (rows of 128, 16-chunk XOR swizzle) ----
  const int rloc = lane >> 4, ch = lane & 15;
#pragma unroll
  for (int t = 0; t < 2; ++t)
#pragma unroll
    for (int i = 0; i < 4; ++i) {
      const int r = w * 16 + i * 4 + rloc;
      const int gc = ch ^ (r & 15);
      gload_lds16(qk + (long)(b * 64 + r) * 1024 + t * 512 + q * 128 + gc * 8,
                  &sm[t * 8192 + (w * 16 + i * 4) * 128]);
    }
  // ---- stage V^T (rows of 64, 8-chunk XOR swizzle) ----
  {
    const int dloc = lane >> 3, pos = lane & 7;
#pragma unroll
    for (int i = 0; i < 4; ++i) {
      const int d = w * 32 + i * 8 + dloc;
      const int gc = pos ^ (d & 7);
      gload_lds16(vtg + (long)(b * 4 + q) * 8192 + (long)d * 64 + gc * 8,
                  &Vt[(w * 32 + i * 8) * 64]);
    }
  }
  __syncthreads();

  // ---- Q/K fragments (HD=32 = one MFMA K-step) ----
  short8 qF[4], kF[4];
  const int pQ = ((w * 4 + quad) ^ l16) * 8;
#pragma unroll
  for (int t = 0; t < 4; ++t) {
    qF[t] = *(const short8*)&sm[0 * 8192 + (t * 16 + l16) * 128 + pQ];
    kF[t] = *(const short8*)&sm[1 * 8192 + (t * 16 + l16) * 128 + pQ];
  }

  f32x4 S[4][4];
#pragma unroll
  for (int mi = 0; mi < 4; ++mi)
#pragma unroll
    for (int ni = 0; ni < 4; ++ni) {
      f32x4 z = {0.f, 0.f, 0.f, 0.f};
      S[mi][ni] = __builtin_amdgcn_mfma_f32_16x16x32_bf16(qF[mi], kF[ni], z, 0, 0, 0);
    }

  // ---- V^T A-fragments: lane = d-row, elems = 8 consecutive k ----
  short8 vA[2][2];
#pragma unroll
  for (int dt = 0; dt < 2; ++dt)
#pragma unroll
    for (int kt = 0; kt < 2; ++kt) {
      const int dl = w * 32 + dt * 16 + l16;
      const int p = (((kt * 4 + quad) ^ (dl & 7))) * 8;
      vA[dt][kt] = *(const short8*)&Vt[dl * 64 + p];
    }

  __syncthreads();  // all Q/K/Vt reads done; P may overwrite Q/K region

  // ---- softmax; P[w][64][72] bf16 (row-major, rows private per wave) ----
  const float* bh = biasx + h * (NTOK * NTOK);
#pragma unroll
  for (int mi = 0; mi < 4; ++mi) {
#pragma unroll
    for (int r = 0; r < 4; ++r) {
      const int row = mi * 16 + quad * 4 + r;
      float vals[4], mx = -3.4e38f;
#pragma unroll
      for (int ni = 0; ni < 4; ++ni) {
        const float s = S[mi][ni][r] * ATT_SCALE + bh[row * 64 + ni * 16 + l16];
        vals[ni] = s;
        mx = fmaxf(mx, s);
      }
#pragma unroll
      for (int d = 1; d < 16; d <<= 1) mx = fmaxf(mx, __shfl_xor(mx, d));
      float sum = 0.f;
#pragma unroll
      for (int ni = 0; ni < 4; ++ni) { vals[ni] = __expf(vals[ni] - mx); sum += vals[ni]; }
#pragma unroll
      for (int d = 1; d < 16; d <<= 1) sum += __shfl_xor(sum, d);
      const float inv = 1.0f / sum;
#pragma unroll
      for (int ni = 0; ni < 4; ++ni)
        P[w * 4608 + row * 72 + ni * 16 + l16] = f2bf(vals[ni] * inv);
    }
  }
  // no block barrier needed: each wave reads only its own P slice (lgkm order)

  // ---- PV: O^T[d][r] = sum_k V^T[d][k] * P[r][k] ----
  f32x4 acc2[2][4] = {};
#pragma unroll
  for (int rt = 0; rt < 4; ++rt)
#pragma unroll
    for (int kt = 0; kt < 2; ++kt) {
      const short8 pF =
          *(const short8*)&P[w * 4608 + (rt * 16 + l16) * 72 + kt * 32 + quad * 8];
#pragma unroll
      for (int dt = 0; dt < 2; ++dt)
        acc2[dt][rt] = __builtin_amdgcn_mfma_f32_16x16x32_bf16(
            vA[dt][kt], pF, acc2[dt][rt], 0, 0, 0);
    }

  __syncthreads();  // all vA/P reads done; Ot may overwrite Vt region

  // ---- repack O^T -> Ot[64][128] (chunk-XOR swizzled) ----
#pragma unroll
  for (int dt = 0; dt < 2; ++dt)
#pragma unroll
    for (int rt = 0; rt < 4; ++rt)
#pragma unroll
      for (int rg = 0; rg < 4; ++rg) {
        const int r = rt * 16 + l16;
        const int c = w * 32 + dt * 16 + quad * 4 + rg;
        const int pos = (c >> 3) ^ (r & 15);
        Ot[r * 128 + pos * 8 + (c & 7)] = f2bf(acc2[dt][rt][rg]);
      }
  __syncthreads();

  // ---- coalesced 16B stores ----
#pragma unroll
  for (int it = 0; it < 4; ++it) {
    const int ci = it * 256 + tid;          // 1024 chunks
    const int row = ci >> 4, p = ci & 15;
    const short8 v = *(const short8*)&Ot[row * 128 + p * 8];
    const int c8 = p ^ (row & 15);
    *(short8*)(aout + (long)(b * 64 + row) * 512 + q * 128 + c8 * 8) = v;
  }
}

extern "C" void kernel_launch(void* const* d_in, const int* in_sizes, int n_in,
                              void* d_out, int out_size, void* d_ws, size_t ws_size,
                              hipStream_t stream) {
  const float* x      = (const float*)d_in[0];
  const float* W_qkv  = (const float*)d_in[1];
  const float* b_qkv  = (const float*)d_in[2];
  const float* W_proj = (const float*)d_in[3];
  const float* b_proj = (const float*)d_in[4];
  const float* btab   = (const float*)d_in[5];

  char* ws = (char*)d_ws;
  unsigned short* qk    = (unsigned short*)ws;                      // 268 MB
  unsigned short* vt    = (unsigned short*)(ws + 268435456L);       // 134 MB
  unsigned short* xb    = (unsigned short*)(ws + 402653184L);       // 134 MB
  unsigned short* aout  = xb;  // xb dead after qkv GEMM; alias
  unsigned short* wqkvb = (unsigned short*)(ws + 536870912L);
  unsigned short* wprjb = (unsigned short*)(ws + 536870912L + 1572864L);
  float*          biasx = (float*)(ws + 536870912L + 1572864L + 524288L);

  cvt_bf16_kernel<<<(MROWS * CDIM) / 1024, 256, 0, stream>>>(x, xb, (MROWS * CDIM) / 4);
  cvt_bf16_kernel<<<(QKVDIM * CDIM) / 1024, 256, 0, stream>>>(W_qkv, wqkvb, (QKVDIM * CDIM) / 4);
  cvt_bf16_kernel<<<(CDIM * CDIM) / 1024, 256, 0, stream>>>(W_proj, wprjb, (CDIM * CDIM) / 4);
  expand_bias_kernel<<<(NHEADS * NTOK * NTOK) / 256, 256, 0, stream>>>(btab, biasx);

  // QKV GEMM: 3072 blocks (512x6), %8==0; writes qk (Q|K) + vt (V^T)
  gemm_qkv_kernel<<<(MROWS / 256) * (QKVDIM / 256), 512, 0, stream>>>(
      xb, wqkvb, b_qkv, qk, vt, MROWS, CDIM, QKVDIM / 256);

  attn_kernel<<<NWIN_B * 4, 256, 0, stream>>>(qk, vt, biasx, aout);

  // proj GEMM: 1024 blocks (512x2), %8==0
  gemm256_kernel<<<(MROWS / 256) * (CDIM / 256), 512, 0, stream>>>(
      aout, wprjb, b_proj, (float*)d_out, MROWS, CDIM, CDIM, CDIM / 256);
}